// Round 1
// baseline (92.298 us; speedup 1.0000x reference)
//
#include <hip/hip_runtime.h>

// loss = sum over flows/channels of mean_{b,h,w} || (I - P_A) patch ||^2
// where P_A projects onto affine functions of patch offsets (a, c).
// Coordinate grids added in the reference are affine in (a,c) -> annihilated.
// Residual via orthonormal basis: r = sumsq - sum^2/kz^2 - (sa^2 + sc^2)/S,
//   sa = sum (a-m) p, sc = sum (c-m) p, m = (kz-1)/2, S = kz * sum_t (t-m)^2.

template<int KZ>
__global__ void patch_loss_kernel(const float* __restrict__ flow,
                                  int W, int Wout, int npix,
                                  float scale, float* __restrict__ partial) {
    const float m = (KZ - 1) * 0.5f;
    float Ssum = 0.f;
#pragma unroll
    for (int t = 0; t < KZ; ++t) Ssum += (t - m) * (t - m);
    const float invS = 1.0f / (Ssum * KZ);
    const float invk2 = 1.0f / (KZ * KZ);
    const int HW = W * W;

    float acc = 0.f;
    for (int idx = blockIdx.x * blockDim.x + threadIdx.x; idx < npix;
         idx += gridDim.x * blockDim.x) {
        int x  = idx % Wout;
        int t1 = idx / Wout;
        int y  = t1 % Wout;
        int bc = t1 / Wout;                 // b*2 + channel
        const float* base = flow + (size_t)bc * HW + (size_t)y * W + x;

        float sum = 0.f, sumsq = 0.f, sa = 0.f, sc = 0.f;
#pragma unroll
        for (int a = 0; a < KZ; ++a) {
#pragma unroll
            for (int c = 0; c < KZ; ++c) {
                float p = base[a * W + c];
                sum   += p;
                sumsq += p * p;
                sa    += (a - m) * p;
                sc    += (c - m) * p;
            }
        }
        acc += sumsq - sum * sum * invk2 - (sa * sa + sc * sc) * invS;
    }

    // block reduction: 64-lane shuffle then LDS across 4 waves
    for (int off = 32; off > 0; off >>= 1) acc += __shfl_down(acc, off);
    __shared__ float red[4];
    int lane = threadIdx.x & 63;
    int wid  = threadIdx.x >> 6;
    if (lane == 0) red[wid] = acc;
    __syncthreads();
    if (threadIdx.x == 0)
        partial[blockIdx.x] = (red[0] + red[1] + red[2] + red[3]) * scale;
}

__global__ void final_reduce_kernel(const float* __restrict__ partial, int n,
                                    float* __restrict__ out) {
    float acc = 0.f;
    for (int i = threadIdx.x; i < n; i += blockDim.x) acc += partial[i];
    for (int off = 32; off > 0; off >>= 1) acc += __shfl_down(acc, off);
    __shared__ float red[4];
    int lane = threadIdx.x & 63;
    int wid  = threadIdx.x >> 6;
    if (lane == 0) red[wid] = acc;
    __syncthreads();
    if (threadIdx.x == 0) out[0] = red[0] + red[1] + red[2] + red[3];
}

extern "C" void kernel_launch(void* const* d_in, const int* in_sizes, int n_in,
                              void* d_out, int out_size, void* d_ws, size_t ws_size,
                              hipStream_t stream) {
    const float* flow0 = (const float*)d_in[0];   // (32, 2, 128, 128)
    const float* flow1 = (const float*)d_in[1];   // (32, 2, 256, 256)
    float* out = (float*)d_out;
    float* partial = (float*)d_ws;

    constexpr int NB0 = 1024;
    constexpr int NB1 = 2048;

    // flow0: kz=3, W=128, Wout=126
    {
        int W = 128, Wout = 126;
        int npix = 32 * 2 * Wout * Wout;            // 1,016,064
        float scale = 1.0f / (32.0f * Wout * Wout); // per-channel mean, channels summed
        patch_loss_kernel<3><<<NB0, 256, 0, stream>>>(flow0, W, Wout, npix, scale,
                                                      partial);
    }
    // flow1: kz=5, W=256, Wout=252
    {
        int W = 256, Wout = 252;
        int npix = 32 * 2 * Wout * Wout;            // 4,064,256
        float scale = 1.0f / (32.0f * Wout * Wout);
        patch_loss_kernel<5><<<NB1, 256, 0, stream>>>(flow1, W, Wout, npix, scale,
                                                      partial + NB0);
    }
    final_reduce_kernel<<<1, 256, 0, stream>>>(partial, NB0 + NB1, out);
}